// Round 17
// baseline (338.867 us; speedup 1.0000x reference)
//
#include <hip/hip_runtime.h>
#include <hip/hip_bf16.h>
#include <stdint.h>

#define B_ 4
#define T_ 2048
#define C_ 1024
#define H_ 16
#define D_ 64

typedef __attribute__((ext_vector_type(8))) short bf16x8;
typedef __attribute__((ext_vector_type(4))) short short4v;
typedef __attribute__((ext_vector_type(4))) float f32x4;

static __device__ __forceinline__ short f2bf(float f) {
    union { float f; unsigned u; } v; v.f = f;
    unsigned r = v.u + 0x7fffu + ((v.u >> 16) & 1u);
    return (short)(r >> 16);
}

static __device__ __forceinline__ float fast_exp2(float x) {
    float r;
    asm("v_exp_f32 %0, %1" : "=v"(r) : "v"(x));
    return r;
}

#define GLD_LDS16(g, l) __builtin_amdgcn_global_load_lds( \
    (const __attribute__((address_space(1))) void*)(g),   \
    (__attribute__((address_space(3))) void*)(l), 16, 0, 0)

// Q pre-scale: (1/32) * log2(e) — folds softmax scale AND exp->exp2 conversion
#define QSCALE 0.04508422f

// ---------------------------------------------------------------------------
// pack_x (round-5 exact)
// ---------------------------------------------------------------------------
__global__ void pack_x(const float* __restrict__ x, short* __restrict__ xb) {
    int t = blockIdx.x * blockDim.x + threadIdx.x;
    const float* src = x + (size_t)t * 8;
    float4 v0 = *(const float4*)src;
    float4 v1 = *(const float4*)(src + 4);
    bf16x8 o;
    o[0] = f2bf(v0.x); o[1] = f2bf(v0.y); o[2] = f2bf(v0.z); o[3] = f2bf(v0.w);
    o[4] = f2bf(v1.x); o[5] = f2bf(v1.y); o[6] = f2bf(v1.z); o[7] = f2bf(v1.w);
    *(bf16x8*)(xb + (size_t)t * 8) = o;
}

// ---------------------------------------------------------------------------
// pack_wqkv2 / pack_wproj2 (round-12 exact, coalesced LDS-transpose)
// ---------------------------------------------------------------------------
__global__ void pack_wqkv2(const float* __restrict__ wq, const float* __restrict__ wk,
                           const float* __restrict__ wv, short* __restrict__ out) {
    __shared__ short tile[64][72];
    const int qh = blockIdx.y;
    const int qkv = qh >> 4, h = qh & 15;
    const int c0 = blockIdx.x * 64;
    const float* w = ((qkv == 0) ? wq : (qkv == 1) ? wk : wv) + (size_t)h * (C_ * D_);
    const int t = threadIdx.x;
    const int r = t >> 2;
    const int dc = (t & 3) * 16;

    const float* src = w + (size_t)(c0 + r) * D_ + dc;
#pragma unroll
    for (int j = 0; j < 4; ++j) {
        float4 v = *(const float4*)(src + j * 4);
        short4v s;
        s[0] = f2bf(v.x); s[1] = f2bf(v.y); s[2] = f2bf(v.z); s[3] = f2bf(v.w);
        *(short4v*)&tile[r][dc + j * 4] = s;
    }
    __syncthreads();

    const int d = t >> 2;
    const int cc = (t & 3) * 16;
    bf16x8 o0, o1;
#pragma unroll
    for (int j = 0; j < 8; ++j) {
        o0[j] = tile[cc + j][d];
        o1[j] = tile[cc + 8 + j][d];
    }
    short* dst = out + ((size_t)qkv * 1024 + h * 64 + d) * C_ + c0 + cc;
    *(bf16x8*)dst = o0;
    *(bf16x8*)(dst + 8) = o1;
}

__global__ void pack_wproj2(const float* __restrict__ wp, short* __restrict__ out) {
    __shared__ short tile[64][72];
    const int c0 = blockIdx.x * 64;
    const int n0 = blockIdx.y * 64;
    const int t = threadIdx.x;
    const int r = t >> 2;
    const int nc = (t & 3) * 16;

    const float* src = wp + (size_t)(c0 + r) * C_ + n0 + nc;
#pragma unroll
    for (int j = 0; j < 4; ++j) {
        float4 v = *(const float4*)(src + j * 4);
        short4v s;
        s[0] = f2bf(v.x); s[1] = f2bf(v.y); s[2] = f2bf(v.z); s[3] = f2bf(v.w);
        *(short4v*)&tile[r][nc + j * 4] = s;
    }
    __syncthreads();

    const int n = t >> 2;
    const int cc = (t & 3) * 16;
    bf16x8 o0, o1;
#pragma unroll
    for (int j = 0; j < 8; ++j) {
        o0[j] = tile[cc + j][n];
        o1[j] = tile[cc + 8 + j][n];
    }
    short* dst = out + (size_t)(n0 + n) * C_ + c0 + cc;
    *(bf16x8*)dst = o0;
    *(bf16x8*)(dst + 8) = o1;
}

// ---------------------------------------------------------------------------
// GEMM v15 (BK=64 + both-sides chunk-XOR, round-15 verified).
// MODE 1: fp32 out + bias.
// MODE 2: QKV split epilogue: Q(scaled)|K -> qk rows; V -> transposed vt.
// ---------------------------------------------------------------------------
template<int MODE>
__global__ __launch_bounds__(256)
void gemm_lds(const short* __restrict__ A, const short* __restrict__ Bt,
              void* __restrict__ Cptr, short* __restrict__ vtptr,
              const float* __restrict__ bias, int M, int N, int K) {
    __shared__ short As[128 * 64];
    __shared__ short Bs[128 * 64];
    const int tid = threadIdx.x;
    const int lane = tid & 63, wid = tid >> 6;
    const int wr = wid >> 1, wc = wid & 1;
    const int l15 = lane & 15, l4 = lane >> 4;
    const int m0 = blockIdx.y * 128, n0 = blockIdx.x * 128;

    f32x4 acc[4][4] = {};

    for (int k0 = 0; k0 < K; k0 += 64) {
#pragma unroll
        for (int p = 0; p < 4; ++p) {
            int e = p * 256 + tid;
            int r = e >> 3, pc = e & 7;
            int lc = pc ^ (r & 7);   // logical 16B k-chunk this slot holds
            GLD_LDS16(A  + (size_t)(m0 + r) * K + k0 + lc * 8, As + e * 8);
            GLD_LDS16(Bt + (size_t)(n0 + r) * K + k0 + lc * 8, Bs + e * 8);
        }
        __syncthreads();

#pragma unroll
        for (int kk = 0; kk < 2; ++kk) {
            bf16x8 af[4], bfr[4];
#pragma unroll
            for (int m = 0; m < 4; ++m) {
                int row = wr * 64 + m * 16 + l15;
                int pc = (kk * 4 + l4) ^ (row & 7);
                af[m] = *(const bf16x8*)(As + row * 64 + pc * 8);
            }
#pragma unroll
            for (int n = 0; n < 4; ++n) {
                int row = wc * 64 + n * 16 + l15;
                int pc = (kk * 4 + l4) ^ (row & 7);
                bfr[n] = *(const bf16x8*)(Bs + row * 64 + pc * 8);
            }
#pragma unroll
            for (int m = 0; m < 4; ++m)
#pragma unroll
                for (int n = 0; n < 4; ++n)
                    acc[m][n] = __builtin_amdgcn_mfma_f32_16x16x32_bf16(af[m], bfr[n], acc[m][n], 0, 0, 0);
        }
        __syncthreads();
    }

#pragma unroll
    for (int m = 0; m < 4; ++m) {
        int row_base = m0 + wr * 64 + m * 16 + l4 * 4;
#pragma unroll
        for (int n = 0; n < 4; ++n) {
            int col = n0 + wc * 64 + n * 16 + l15;
            if (MODE == 1) {
#pragma unroll
                for (int r = 0; r < 4; ++r)
                    ((float*)Cptr)[(size_t)(row_base + r) * N + col] =
                        acc[m][n][r] + bias[col];
            } else {  // MODE 2
                if (col < 2048) {  // Q (scaled) | K
                    float q = (col < 1024) ? QSCALE : 1.0f;
#pragma unroll
                    for (int r = 0; r < 4; ++r)
                        ((short*)Cptr)[(size_t)(row_base + r) * 2048 + col] =
                            f2bf(acc[m][n][r] * q);
                } else {           // V: transposed scatter
                    int cm = col - 2048;
                    int bq = row_base >> 11, t = row_base & 2047;
                    short4v s;
                    s[0] = f2bf(acc[m][n][0]); s[1] = f2bf(acc[m][n][1]);
                    s[2] = f2bf(acc[m][n][2]); s[3] = f2bf(acc[m][n][3]);
                    *(short4v*)(vtptr + ((size_t)bq * 1024 + cm) * 2048 + t) = s;
                }
            }
        }
    }
}

// ---------------------------------------------------------------------------
// Flash attention v17 = v16 mechanics (pair-tile, GLD V-staging, exp2+defer)
// on 8-WAVE blocks over 128-row strip pairs:
//   block (pi,bh): strip A rows [pi*128,+128), strip B rows [(15-pi)*128,+128);
//   wave w owns rows qA0+w*16 / qB0+w*16 (per-wave regs unchanged).
//   V staged once per 8 waves; block-phases halve -> barrier events halve.
//   Per-wave causal: strip active iff t <= last (A: 2pi+(w>>2);
//   B: 30-2pi+(w>>2)), diag at equality. nt = 32-2pi (always even).
// ---------------------------------------------------------------------------
__device__ __forceinline__ void softmax_phase(
    f32x4 S[4], f32x4 O[4], float* mrow, float* srow,
    int qrow0, int s0, bool diag, int l15, int l4, short* ps) {
    float pmax[4];
#pragma unroll
    for (int r = 0; r < 4; ++r) pmax[r] = -1e30f;
#pragma unroll
    for (int n = 0; n < 4; ++n) {
#pragma unroll
        for (int r = 0; r < 4; ++r) {
            float v = S[n][r];   // already scaled + in log2 domain
            if (diag) {
                int scol = s0 + n * 16 + l15;
                if (scol > qrow0 + r) v = -1e30f;
            }
            S[n][r] = v;
            pmax[r] = fmaxf(pmax[r], v);
        }
    }
#pragma unroll
    for (int r = 0; r < 4; ++r) {
        float v = pmax[r];
        v = fmaxf(v, __shfl_xor(v, 1));
        v = fmaxf(v, __shfl_xor(v, 2));
        v = fmaxf(v, __shfl_xor(v, 4));
        v = fmaxf(v, __shfl_xor(v, 8));
        pmax[r] = v;
    }
    // defer-max: skip O/s rescale while max growth <= 8 (P bounded by 2^8)
    int ok = (pmax[0] <= mrow[0] + 8.0f) & (pmax[1] <= mrow[1] + 8.0f) &
             (pmax[2] <= mrow[2] + 8.0f) & (pmax[3] <= mrow[3] + 8.0f);
    if (!__all(ok)) {
#pragma unroll
        for (int r = 0; r < 4; ++r) {
            float mnew = fmaxf(mrow[r], pmax[r]);
            float fr = fast_exp2(mrow[r] - mnew);
            mrow[r] = mnew;
            srow[r] *= fr;
#pragma unroll
            for (int n = 0; n < 4; ++n) O[n][r] *= fr;
        }
    }
    float psum[4];
#pragma unroll
    for (int r = 0; r < 4; ++r) psum[r] = 0.0f;
#pragma unroll
    for (int n = 0; n < 4; ++n) {
#pragma unroll
        for (int r = 0; r < 4; ++r) {
            float p = fast_exp2(S[n][r] - mrow[r]);
            psum[r] += p;
            ps[(l4 * 4 + r) * 72 + n * 16 + l15] = f2bf(p);
        }
    }
#pragma unroll
    for (int r = 0; r < 4; ++r) {
        float v = psum[r];
        v += __shfl_xor(v, 1);
        v += __shfl_xor(v, 2);
        v += __shfl_xor(v, 4);
        v += __shfl_xor(v, 8);
        srow[r] += v;
    }
}

__global__ __launch_bounds__(512)
void attn_v17(const short* __restrict__ qk, const short* __restrict__ vt,
              short* __restrict__ out) {
    const int pi = blockIdx.x;        // 0..7  (128-row strip pair)
    const int bh = blockIdx.y;        // 0..63
    const int b = bh >> 4;
    const int h = bh & 15;
    const int tid = threadIdx.x;
    const int wave = tid >> 6;        // 0..7
    const int lane = tid & 63;
    const int l15 = lane & 15, l4 = lane >> 4;

    const int qA0 = pi * 128 + wave * 16;          // this wave's A rows
    const int qB0 = (15 - pi) * 128 + wave * 16;   // this wave's B rows
    const int lastA = 2 * pi + (wave >> 2);        // A active for t <= lastA
    const int lastB = 30 - 2 * pi + (wave >> 2);   // B active for t <= lastB
    const int nt = 32 - 2 * pi;                    // block phases (even)

    __shared__ short Vt[2][64][64];     // linear GLD dest; source-swizzled
    __shared__ short Ps[8][2][16][72];  // per-wave, per-strip P buffer

    const size_t rs = 2 * C_;  // 2048
    const short* qbA = qk + ((size_t)b * T_ + qA0) * rs + h * 64;
    const short* qbB = qk + ((size_t)b * T_ + qB0) * rs + h * 64;
    const short* kb  = qk + (size_t)b * T_ * rs + 1024 + h * 64;
    const short* vtb = vt + (size_t)bh * 64 * T_;   // V^T rows [d][t]

    bf16x8 aqA0 = *(const bf16x8*)(qbA + (size_t)l15 * rs + l4 * 8);
    bf16x8 aqA1 = *(const bf16x8*)(qbA + (size_t)l15 * rs + 32 + l4 * 8);
    bf16x8 aqB0 = *(const bf16x8*)(qbB + (size_t)l15 * rs + l4 * 8);
    bf16x8 aqB1 = *(const bf16x8*)(qbB + (size_t)l15 * rs + 32 + l4 * 8);

    f32x4 OA[4] = {}, OB[4] = {};
    float mA[4], sA[4], mB[4], sB[4];
#pragma unroll
    for (int r = 0; r < 4; ++r) { mA[r] = mB[r] = -1e30f; sA[r] = sB[r] = 0.0f; }

    short* psB = &Ps[wave][0][0][0];
    short* psA = &Ps[wave][1][0][0];
    const int qrB = qB0 + l4 * 4;
    const int qrA = qA0 + l4 * 4;

    // staging: 512 threads cover one 64x64 tile (1 GLD each), chunk-XOR source
    const int sr = tid >> 3;     // row 0..63
    const int spc = tid & 7;     // physical 16B chunk

    auto stage = [&](int slot, int s0) {
        int lc = spc ^ (sr & 7);
        GLD_LDS16(vtb + (size_t)sr * T_ + s0 + lc * 8,
                  &Vt[slot][0][0] + tid * 8);
    };

    auto qk_sm = [&](int s0, bool actB, bool diagB, bool actA, bool diagA) {
        bf16x8 bk0[4], bk1[4];
#pragma unroll
        for (int n = 0; n < 4; ++n) {
            const short* kr = kb + (size_t)(s0 + n * 16 + l15) * rs;
            bk0[n] = *(const bf16x8*)(kr + l4 * 8);
            bk1[n] = *(const bf16x8*)(kr + 32 + l4 * 8);
        }
        if (actB) {
            f32x4 S[4];
#pragma unroll
            for (int n = 0; n < 4; ++n) {
                f32x4 z = {};
                z = __builtin_amdgcn_mfma_f32_16x16x32_bf16(aqB0, bk0[n], z, 0, 0, 0);
                S[n] = __builtin_amdgcn_mfma_f32_16x16x32_bf16(aqB1, bk1[n], z, 0, 0, 0);
            }
            softmax_phase(S, OB, mB, sB, qrB, s0, diagB, l15, l4, psB);
        }
        if (actA) {
            f32x4 SA[4];
#pragma unroll
            for (int n = 0; n < 4; ++n) {
                f32x4 z = {};
                z = __builtin_amdgcn_mfma_f32_16x16x32_bf16(aqA0, bk0[n], z, 0, 0, 0);
                SA[n] = __builtin_amdgcn_mfma_f32_16x16x32_bf16(aqA1, bk1[n], z, 0, 0, 0);
            }
            softmax_phase(SA, OA, mA, sA, qrA, s0, diagA, l15, l4, psA);
        }
    };

    auto pv = [&](int slot, bool actB, bool actA) {
        const int x7 = l15 & 7;
        if (actB) {
            bf16x8 apB0 = *(const bf16x8*)(psB + l15 * 72 + l4 * 8);
            bf16x8 apB1 = *(const bf16x8*)(psB + l15 * 72 + 32 + l4 * 8);
#pragma unroll
            for (int n = 0; n < 4; ++n) {
                const short* vrow = &Vt[slot][n * 16 + l15][0];
                bf16x8 bv0 = *(const bf16x8*)(vrow + ((l4 ^ x7) * 8));
                bf16x8 bv1 = *(const bf16x8*)(vrow + (((l4 + 4) ^ x7) * 8));
                OB[n] = __builtin_amdgcn_mfma_f32_16x16x32_bf16(apB0, bv0, OB[n], 0, 0, 0);
                OB[n] = __builtin_amdgcn_mfma_f32_16x16x32_bf16(apB1, bv1, OB[n], 0, 0, 0);
            }
        }
        if (actA) {
            bf16x8 apA0 = *(const bf16x8*)(psA + l15 * 72 + l4 * 8);
            bf16x8 apA1 = *(const bf16x8*)(psA + l15 * 72 + 32 + l4 * 8);
#pragma unroll
            for (int n = 0; n < 4; ++n) {
                const short* vrow = &Vt[slot][n * 16 + l15][0];
                bf16x8 bv0 = *(const bf16x8*)(vrow + ((l4 ^ x7) * 8));
                bf16x8 bv1 = *(const bf16x8*)(vrow + (((l4 + 4) ^ x7) * 8));
                OA[n] = __builtin_amdgcn_mfma_f32_16x16x32_bf16(apA0, bv0, OA[n], 0, 0, 0);
                OA[n] = __builtin_amdgcn_mfma_f32_16x16x32_bf16(apA1, bv1, OA[n], 0, 0, 0);
            }
        }
    };

    for (int t = 0; t < nt; t += 2) {
        const int s0 = t * 64;
        __syncthreads();  // both Vt slots free (all PV reads of prev pair done)

        stage(0, s0);
        stage(1, s0 + 64);

        qk_sm(s0, t <= lastB, t == lastB, t <= lastA, t == lastA);

        __syncthreads();  // vmcnt(0): V staged; Ps(t) drained

        pv(0, t <= lastB, t <= lastA);
        qk_sm(s0 + 64, t + 1 <= lastB, t + 1 == lastB, t + 1 <= lastA, t + 1 == lastA);

        asm volatile("s_waitcnt lgkmcnt(0)" ::: "memory");
        __builtin_amdgcn_sched_barrier(0);

        pv(1, t + 1 <= lastB, t + 1 <= lastA);
    }

    // ---- normalize + store both strips ----
#pragma unroll
    for (int r = 0; r < 4; ++r) {
        int rowB = qB0 + l4 * 4 + r;
        int rowA = qA0 + l4 * 4 + r;
        float invB = 1.0f / sB[r];
        float invA = 1.0f / sA[r];
        size_t obB = ((size_t)b * T_ + rowB) * C_ + h * 64;
        size_t obA = ((size_t)b * T_ + rowA) * C_ + h * 64;
#pragma unroll
        for (int n = 0; n < 4; ++n) {
            out[obB + n * 16 + l15] = f2bf(OB[n][r] * invB);
            out[obA + n * 16 + l15] = f2bf(OA[n][r] * invA);
        }
    }
}

// ---------------------------------------------------------------------------
extern "C" void kernel_launch(void* const* d_in, const int* in_sizes, int n_in,
                              void* d_out, int out_size, void* d_ws, size_t ws_size,
                              hipStream_t stream) {
    const float* x     = (const float*)d_in[0];
    const float* wq    = (const float*)d_in[1];
    const float* wk    = (const float*)d_in[2];
    const float* wv    = (const float*)d_in[3];
    const float* wproj = (const float*)d_in[4];
    const float* bproj = (const float*)d_in[5];
    float* out = (float*)d_out;

    // workspace (shorts): wqkv_t | wproj_t | qk_b | vt_b | attn_b (xb alias)
    short* wqkv_t  = (short*)d_ws;                   // 3072*1024
    short* wproj_t = wqkv_t + 3072 * 1024;           // 1024*1024
    short* qk_b    = wproj_t + 1024 * 1024;          // 8192*2048  (Q|K)
    short* vt_b    = qk_b + (size_t)8192 * 2048;     // 64*64*2048 (V^T)
    short* attn_b  = vt_b + (size_t)64 * 64 * 2048;  // 8192*1024 (xb alias)
    short* xb      = attn_b;
    // total = 75,497,472 bytes (identical to all prior rounds)

    pack_x<<<4096, 256, 0, stream>>>(x, xb);
    pack_wqkv2<<<dim3(16, 48), 256, 0, stream>>>(wq, wk, wv, wqkv_t);
    pack_wproj2<<<dim3(16, 16), 256, 0, stream>>>(wproj, wproj_t);

    // QKV projection: Q(scaled)|K -> qk_b, V^T -> vt_b
    gemm_lds<2><<<dim3(24, 64), 256, 0, stream>>>(
        xb, wqkv_t, qk_b, vt_b, nullptr, 8192, 3072, 1024);

    // flash attention: 8-wave blocks, 128-row strip pairs, pair-tile phases
    attn_v17<<<dim3(8, 64), 512, 0, stream>>>(qk_b, vt_b, attn_b);

    // output projection: [8192,1024] x [1024,1024] + bias -> fp32
    gemm_lds<1><<<dim3(8, 64), 256, 0, stream>>>(
        attn_b, wproj_t, out, nullptr, bproj, 8192, 1024, 1024);
}

// Round 18
// 268.432 us; speedup vs baseline: 1.2624x; 1.2624x over previous
//
#include <hip/hip_runtime.h>
#include <hip/hip_bf16.h>
#include <stdint.h>

#define B_ 4
#define T_ 2048
#define C_ 1024
#define H_ 16
#define D_ 64

typedef __attribute__((ext_vector_type(8))) short bf16x8;
typedef __attribute__((ext_vector_type(4))) short short4v;
typedef __attribute__((ext_vector_type(4))) float f32x4;

static __device__ __forceinline__ short f2bf(float f) {
    union { float f; unsigned u; } v; v.f = f;
    unsigned r = v.u + 0x7fffu + ((v.u >> 16) & 1u);
    return (short)(r >> 16);
}

static __device__ __forceinline__ float fast_exp2(float x) {
    float r;
    asm("v_exp_f32 %0, %1" : "=v"(r) : "v"(x));
    return r;
}

#define GLD_LDS16(g, l) __builtin_amdgcn_global_load_lds( \
    (const __attribute__((address_space(1))) void*)(g),   \
    (__attribute__((address_space(3))) void*)(l), 16, 0, 0)

// Q pre-scale: (1/32) * log2(e) — folds softmax scale AND exp->exp2 conversion
#define QSCALE 0.04508422f

// ---------------------------------------------------------------------------
// pack_x (round-5 exact)
// ---------------------------------------------------------------------------
__global__ void pack_x(const float* __restrict__ x, short* __restrict__ xb) {
    int t = blockIdx.x * blockDim.x + threadIdx.x;
    const float* src = x + (size_t)t * 8;
    float4 v0 = *(const float4*)src;
    float4 v1 = *(const float4*)(src + 4);
    bf16x8 o;
    o[0] = f2bf(v0.x); o[1] = f2bf(v0.y); o[2] = f2bf(v0.z); o[3] = f2bf(v0.w);
    o[4] = f2bf(v1.x); o[5] = f2bf(v1.y); o[6] = f2bf(v1.z); o[7] = f2bf(v1.w);
    *(bf16x8*)(xb + (size_t)t * 8) = o;
}

// ---------------------------------------------------------------------------
// pack_wqkv2 / pack_wproj2 (round-12 exact, coalesced LDS-transpose)
// ---------------------------------------------------------------------------
__global__ void pack_wqkv2(const float* __restrict__ wq, const float* __restrict__ wk,
                           const float* __restrict__ wv, short* __restrict__ out) {
    __shared__ short tile[64][72];
    const int qh = blockIdx.y;
    const int qkv = qh >> 4, h = qh & 15;
    const int c0 = blockIdx.x * 64;
    const float* w = ((qkv == 0) ? wq : (qkv == 1) ? wk : wv) + (size_t)h * (C_ * D_);
    const int t = threadIdx.x;
    const int r = t >> 2;
    const int dc = (t & 3) * 16;

    const float* src = w + (size_t)(c0 + r) * D_ + dc;
#pragma unroll
    for (int j = 0; j < 4; ++j) {
        float4 v = *(const float4*)(src + j * 4);
        short4v s;
        s[0] = f2bf(v.x); s[1] = f2bf(v.y); s[2] = f2bf(v.z); s[3] = f2bf(v.w);
        *(short4v*)&tile[r][dc + j * 4] = s;
    }
    __syncthreads();

    const int d = t >> 2;
    const int cc = (t & 3) * 16;
    bf16x8 o0, o1;
#pragma unroll
    for (int j = 0; j < 8; ++j) {
        o0[j] = tile[cc + j][d];
        o1[j] = tile[cc + 8 + j][d];
    }
    short* dst = out + ((size_t)qkv * 1024 + h * 64 + d) * C_ + c0 + cc;
    *(bf16x8*)dst = o0;
    *(bf16x8*)(dst + 8) = o1;
}

__global__ void pack_wproj2(const float* __restrict__ wp, short* __restrict__ out) {
    __shared__ short tile[64][72];
    const int c0 = blockIdx.x * 64;
    const int n0 = blockIdx.y * 64;
    const int t = threadIdx.x;
    const int r = t >> 2;
    const int nc = (t & 3) * 16;

    const float* src = wp + (size_t)(c0 + r) * C_ + n0 + nc;
#pragma unroll
    for (int j = 0; j < 4; ++j) {
        float4 v = *(const float4*)(src + j * 4);
        short4v s;
        s[0] = f2bf(v.x); s[1] = f2bf(v.y); s[2] = f2bf(v.z); s[3] = f2bf(v.w);
        *(short4v*)&tile[r][nc + j * 4] = s;
    }
    __syncthreads();

    const int n = t >> 2;
    const int cc = (t & 3) * 16;
    bf16x8 o0, o1;
#pragma unroll
    for (int j = 0; j < 8; ++j) {
        o0[j] = tile[cc + j][n];
        o1[j] = tile[cc + 8 + j][n];
    }
    short* dst = out + (size_t)(n0 + n) * C_ + c0 + cc;
    *(bf16x8*)dst = o0;
    *(bf16x8*)(dst + 8) = o1;
}

// ---------------------------------------------------------------------------
// GEMM v15 (BK=64 + both-sides chunk-XOR) + T1 XCD-aware block swizzle
// (bijective: grid sizes 1536 / 512, both % 8 == 0).
// MODE 1: fp32 out + bias.
// MODE 2: QKV split epilogue: Q(scaled)|K -> qk rows; V -> transposed vt.
// ---------------------------------------------------------------------------
template<int MODE>
__global__ __launch_bounds__(256)
void gemm_lds(const short* __restrict__ A, const short* __restrict__ Bt,
              void* __restrict__ Cptr, short* __restrict__ vtptr,
              const float* __restrict__ bias, int M, int N, int K) {
    __shared__ short As[128 * 64];
    __shared__ short Bs[128 * 64];
    const int tid = threadIdx.x;
    const int lane = tid & 63, wid = tid >> 6;
    const int wr = wid >> 1, wc = wid & 1;
    const int l15 = lane & 15, l4 = lane >> 4;

    // T1: XCD-aware block remap (8 XCDs; nwg % 8 == 0 -> simple bijection)
    const int nwg = gridDim.x * gridDim.y;
    const int bid = blockIdx.y * gridDim.x + blockIdx.x;
    const int cpx = nwg >> 3;
    const int swz = (bid & 7) * cpx + (bid >> 3);
    const int m0 = (swz / gridDim.x) * 128;
    const int n0 = (swz % gridDim.x) * 128;

    f32x4 acc[4][4] = {};

    for (int k0 = 0; k0 < K; k0 += 64) {
#pragma unroll
        for (int p = 0; p < 4; ++p) {
            int e = p * 256 + tid;
            int r = e >> 3, pc = e & 7;
            int lc = pc ^ (r & 7);   // logical 16B k-chunk this slot holds
            GLD_LDS16(A  + (size_t)(m0 + r) * K + k0 + lc * 8, As + e * 8);
            GLD_LDS16(Bt + (size_t)(n0 + r) * K + k0 + lc * 8, Bs + e * 8);
        }
        __syncthreads();

#pragma unroll
        for (int kk = 0; kk < 2; ++kk) {
            bf16x8 af[4], bfr[4];
#pragma unroll
            for (int m = 0; m < 4; ++m) {
                int row = wr * 64 + m * 16 + l15;
                int pc = (kk * 4 + l4) ^ (row & 7);
                af[m] = *(const bf16x8*)(As + row * 64 + pc * 8);
            }
#pragma unroll
            for (int n = 0; n < 4; ++n) {
                int row = wc * 64 + n * 16 + l15;
                int pc = (kk * 4 + l4) ^ (row & 7);
                bfr[n] = *(const bf16x8*)(Bs + row * 64 + pc * 8);
            }
#pragma unroll
            for (int m = 0; m < 4; ++m)
#pragma unroll
                for (int n = 0; n < 4; ++n)
                    acc[m][n] = __builtin_amdgcn_mfma_f32_16x16x32_bf16(af[m], bfr[n], acc[m][n], 0, 0, 0);
        }
        __syncthreads();
    }

#pragma unroll
    for (int m = 0; m < 4; ++m) {
        int row_base = m0 + wr * 64 + m * 16 + l4 * 4;
#pragma unroll
        for (int n = 0; n < 4; ++n) {
            int col = n0 + wc * 64 + n * 16 + l15;
            if (MODE == 1) {
#pragma unroll
                for (int r = 0; r < 4; ++r)
                    ((float*)Cptr)[(size_t)(row_base + r) * N + col] =
                        acc[m][n][r] + bias[col];
            } else {  // MODE 2
                if (col < 2048) {  // Q (scaled) | K
                    float q = (col < 1024) ? QSCALE : 1.0f;
#pragma unroll
                    for (int r = 0; r < 4; ++r)
                        ((short*)Cptr)[(size_t)(row_base + r) * 2048 + col] =
                            f2bf(acc[m][n][r] * q);
                } else {           // V: transposed scatter
                    int cm = col - 2048;
                    int bq = row_base >> 11, t = row_base & 2047;
                    short4v s;
                    s[0] = f2bf(acc[m][n][0]); s[1] = f2bf(acc[m][n][1]);
                    s[2] = f2bf(acc[m][n][2]); s[3] = f2bf(acc[m][n][3]);
                    *(short4v*)(vtptr + ((size_t)bq * 1024 + cm) * 2048 + t) = s;
                }
            }
        }
    }
}

// ---------------------------------------------------------------------------
// Flash attention v16 (round-16 exact — measured best, 172 µs). Frozen.
// ---------------------------------------------------------------------------
__device__ __forceinline__ void softmax_phase(
    f32x4 S[4], f32x4 O[4], float* mrow, float* srow,
    int qrow0, int s0, bool diag, int l15, int l4, short* ps) {
    float pmax[4];
#pragma unroll
    for (int r = 0; r < 4; ++r) pmax[r] = -1e30f;
#pragma unroll
    for (int n = 0; n < 4; ++n) {
#pragma unroll
        for (int r = 0; r < 4; ++r) {
            float v = S[n][r];   // already scaled + in log2 domain
            if (diag) {
                int scol = s0 + n * 16 + l15;
                if (scol > qrow0 + r) v = -1e30f;
            }
            S[n][r] = v;
            pmax[r] = fmaxf(pmax[r], v);
        }
    }
#pragma unroll
    for (int r = 0; r < 4; ++r) {
        float v = pmax[r];
        v = fmaxf(v, __shfl_xor(v, 1));
        v = fmaxf(v, __shfl_xor(v, 2));
        v = fmaxf(v, __shfl_xor(v, 4));
        v = fmaxf(v, __shfl_xor(v, 8));
        pmax[r] = v;
    }
    // defer-max: skip O/s rescale while max growth <= 8 (P bounded by 2^8)
    int ok = (pmax[0] <= mrow[0] + 8.0f) & (pmax[1] <= mrow[1] + 8.0f) &
             (pmax[2] <= mrow[2] + 8.0f) & (pmax[3] <= mrow[3] + 8.0f);
    if (!__all(ok)) {
#pragma unroll
        for (int r = 0; r < 4; ++r) {
            float mnew = fmaxf(mrow[r], pmax[r]);
            float fr = fast_exp2(mrow[r] - mnew);
            mrow[r] = mnew;
            srow[r] *= fr;
#pragma unroll
            for (int n = 0; n < 4; ++n) O[n][r] *= fr;
        }
    }
    float psum[4];
#pragma unroll
    for (int r = 0; r < 4; ++r) psum[r] = 0.0f;
#pragma unroll
    for (int n = 0; n < 4; ++n) {
#pragma unroll
        for (int r = 0; r < 4; ++r) {
            float p = fast_exp2(S[n][r] - mrow[r]);
            psum[r] += p;
            ps[(l4 * 4 + r) * 72 + n * 16 + l15] = f2bf(p);
        }
    }
#pragma unroll
    for (int r = 0; r < 4; ++r) {
        float v = psum[r];
        v += __shfl_xor(v, 1);
        v += __shfl_xor(v, 2);
        v += __shfl_xor(v, 4);
        v += __shfl_xor(v, 8);
        srow[r] += v;
    }
}

__global__ __launch_bounds__(256)
void attn_v16(const short* __restrict__ qk, const short* __restrict__ vt,
              short* __restrict__ out) {
    const int pi = blockIdx.x;        // 0..15  (strip pair)
    const int bh = blockIdx.y;        // 0..63
    const int b = bh >> 4;
    const int h = bh & 15;
    const int qA0 = pi * 64;
    const int qB0 = (31 - pi) * 64;
    const int ntA = pi + 1;
    const int ntB = 32 - pi;
    const int tid = threadIdx.x;
    const int wave = tid >> 6;
    const int lane = tid & 63;
    const int l15 = lane & 15, l4 = lane >> 4;

    __shared__ short Vt[2][64][64];     // linear (GLD dest); source-swizzled
    __shared__ short Ps[4][2][16][72];  // per-wave, per-strip P buffer

    const size_t rs = 2 * C_;  // 2048
    const short* qbA = qk + ((size_t)b * T_ + qA0) * rs + h * 64;
    const short* qbB = qk + ((size_t)b * T_ + qB0) * rs + h * 64;
    const short* kb  = qk + (size_t)b * T_ * rs + 1024 + h * 64;
    const short* vtb = vt + (size_t)bh * 64 * T_;   // V^T rows [d][t]

    bf16x8 aqA0 = *(const bf16x8*)(qbA + (size_t)(wave * 16 + l15) * rs + l4 * 8);
    bf16x8 aqA1 = *(const bf16x8*)(qbA + (size_t)(wave * 16 + l15) * rs + 32 + l4 * 8);
    bf16x8 aqB0 = *(const bf16x8*)(qbB + (size_t)(wave * 16 + l15) * rs + l4 * 8);
    bf16x8 aqB1 = *(const bf16x8*)(qbB + (size_t)(wave * 16 + l15) * rs + 32 + l4 * 8);

    f32x4 OA[4] = {}, OB[4] = {};
    float mA[4], sA[4], mB[4], sB[4];
#pragma unroll
    for (int r = 0; r < 4; ++r) { mA[r] = mB[r] = -1e30f; sA[r] = sB[r] = 0.0f; }

    short* psB = &Ps[wave][0][0][0];
    short* psA = &Ps[wave][1][0][0];
    const int qrB = qB0 + wave * 16 + l4 * 4;
    const int qrA = qA0 + wave * 16 + l4 * 4;

    // staging geometry: slot e covers row r=e>>3, physical chunk pc=e&7;
    // source column chunk lc = pc ^ (r&7)  (both-sides XOR swizzle)
    const int sr = tid >> 3;                 // row this thread covers (p=0)
    const int spc = tid & 7;

    auto stage = [&](int slot, int s0) {
#pragma unroll
        for (int p = 0; p < 2; ++p) {
            int e = p * 256 + tid;
            int r = (p == 0) ? sr : (sr + 32);
            int lc = spc ^ (r & 7);
            GLD_LDS16(vtb + (size_t)r * T_ + s0 + lc * 8,
                      &Vt[slot][0][0] + e * 8);
        }
    };

    auto qk_sm = [&](int s0, bool actA) {
        bf16x8 bk0[4], bk1[4];
#pragma unroll
        for (int n = 0; n < 4; ++n) {
            const short* kr = kb + (size_t)(s0 + n * 16 + l15) * rs;
            bk0[n] = *(const bf16x8*)(kr + l4 * 8);
            bk1[n] = *(const bf16x8*)(kr + 32 + l4 * 8);
        }
        f32x4 S[4];
#pragma unroll
        for (int n = 0; n < 4; ++n) {
            f32x4 z = {};
            z = __builtin_amdgcn_mfma_f32_16x16x32_bf16(aqB0, bk0[n], z, 0, 0, 0);
            S[n] = __builtin_amdgcn_mfma_f32_16x16x32_bf16(aqB1, bk1[n], z, 0, 0, 0);
        }
        softmax_phase(S, OB, mB, sB, qrB, s0, s0 == qB0, l15, l4, psB);
        if (actA) {
            f32x4 SA[4];
#pragma unroll
            for (int n = 0; n < 4; ++n) {
                f32x4 z = {};
                z = __builtin_amdgcn_mfma_f32_16x16x32_bf16(aqA0, bk0[n], z, 0, 0, 0);
                SA[n] = __builtin_amdgcn_mfma_f32_16x16x32_bf16(aqA1, bk1[n], z, 0, 0, 0);
            }
            softmax_phase(SA, OA, mA, sA, qrA, s0, s0 == qA0, l15, l4, psA);
        }
    };

    auto pv = [&](int slot, bool actA) {
        bf16x8 apB0 = *(const bf16x8*)(psB + l15 * 72 + l4 * 8);
        bf16x8 apB1 = *(const bf16x8*)(psB + l15 * 72 + 32 + l4 * 8);
        const int x7 = l15 & 7;
#pragma unroll
        for (int n = 0; n < 4; ++n) {
            const short* vrow = &Vt[slot][n * 16 + l15][0];
            bf16x8 bv0 = *(const bf16x8*)(vrow + ((l4 ^ x7) * 8));
            bf16x8 bv1 = *(const bf16x8*)(vrow + (((l4 + 4) ^ x7) * 8));
            OB[n] = __builtin_amdgcn_mfma_f32_16x16x32_bf16(apB0, bv0, OB[n], 0, 0, 0);
            OB[n] = __builtin_amdgcn_mfma_f32_16x16x32_bf16(apB1, bv1, OB[n], 0, 0, 0);
        }
        if (actA) {
            bf16x8 apA0 = *(const bf16x8*)(psA + l15 * 72 + l4 * 8);
            bf16x8 apA1 = *(const bf16x8*)(psA + l15 * 72 + 32 + l4 * 8);
#pragma unroll
            for (int n = 0; n < 4; ++n) {
                const short* vrow = &Vt[slot][n * 16 + l15][0];
                bf16x8 bv0 = *(const bf16x8*)(vrow + ((l4 ^ x7) * 8));
                bf16x8 bv1 = *(const bf16x8*)(vrow + (((l4 + 4) ^ x7) * 8));
                OA[n] = __builtin_amdgcn_mfma_f32_16x16x32_bf16(apA0, bv0, OA[n], 0, 0, 0);
                OA[n] = __builtin_amdgcn_mfma_f32_16x16x32_bf16(apA1, bv1, OA[n], 0, 0, 0);
            }
        }
    };

    const int npair = ntB & ~1;
    for (int t = 0; t < npair; t += 2) {
        const int s0 = t * 64;
        __syncthreads();  // both Vt slots free (all PV reads of prev pair done)

        // ---- issue V(t), V(t+1) via global_load_lds (fire-and-forget) ----
        stage(0, s0);
        stage(1, s0 + 64);

        qk_sm(s0, t < ntA);   // GLD latency hides under QK^T + softmax

        __syncthreads();      // vmcnt(0): V staged; Ps(t) drained

        pv(0, t < ntA);
        qk_sm(s0 + 64, t + 1 < ntA);

        asm volatile("s_waitcnt lgkmcnt(0)" ::: "memory");
        __builtin_amdgcn_sched_barrier(0);

        pv(1, t + 1 < ntA);
    }

    if (ntB & 1) {  // odd tail: single tile
        const int s0 = npair * 64;
        __syncthreads();
        stage(0, s0);
        qk_sm(s0, npair < ntA);
        __syncthreads();
        pv(0, npair < ntA);
    }

    // ---- normalize + store both strips ----
#pragma unroll
    for (int r = 0; r < 4; ++r) {
        int rowB = qB0 + wave * 16 + l4 * 4 + r;
        int rowA = qA0 + wave * 16 + l4 * 4 + r;
        float invB = 1.0f / sB[r];
        float invA = 1.0f / sA[r];
        size_t obB = ((size_t)b * T_ + rowB) * C_ + h * 64;
        size_t obA = ((size_t)b * T_ + rowA) * C_ + h * 64;
#pragma unroll
        for (int n = 0; n < 4; ++n) {
            out[obB + n * 16 + l15] = f2bf(OB[n][r] * invB);
            out[obA + n * 16 + l15] = f2bf(OA[n][r] * invA);
        }
    }
}

// ---------------------------------------------------------------------------
extern "C" void kernel_launch(void* const* d_in, const int* in_sizes, int n_in,
                              void* d_out, int out_size, void* d_ws, size_t ws_size,
                              hipStream_t stream) {
    const float* x     = (const float*)d_in[0];
    const float* wq    = (const float*)d_in[1];
    const float* wk    = (const float*)d_in[2];
    const float* wv    = (const float*)d_in[3];
    const float* wproj = (const float*)d_in[4];
    const float* bproj = (const float*)d_in[5];
    float* out = (float*)d_out;

    // workspace (shorts): wqkv_t | wproj_t | qk_b | vt_b | attn_b (xb alias)
    short* wqkv_t  = (short*)d_ws;                   // 3072*1024
    short* wproj_t = wqkv_t + 3072 * 1024;           // 1024*1024
    short* qk_b    = wproj_t + 1024 * 1024;          // 8192*2048  (Q|K)
    short* vt_b    = qk_b + (size_t)8192 * 2048;     // 64*64*2048 (V^T)
    short* attn_b  = vt_b + (size_t)64 * 64 * 2048;  // 8192*1024 (xb alias)
    short* xb      = attn_b;
    // total = 75,497,472 bytes (identical to all prior rounds)

    pack_x<<<4096, 256, 0, stream>>>(x, xb);
    pack_wqkv2<<<dim3(16, 48), 256, 0, stream>>>(wq, wk, wv, wqkv_t);
    pack_wproj2<<<dim3(16, 16), 256, 0, stream>>>(wproj, wproj_t);

    // QKV projection: Q(scaled)|K -> qk_b, V^T -> vt_b
    gemm_lds<2><<<dim3(24, 64), 256, 0, stream>>>(
        xb, wqkv_t, qk_b, vt_b, nullptr, 8192, 3072, 1024);

    // flash attention, pair-tile phases, GLD V-staging (round-16 best)
    attn_v16<<<dim3(16, 64), 256, 0, stream>>>(qk_b, vt_b, attn_b);

    // output projection: [8192,1024] x [1024,1024] + bias -> fp32
    gemm_lds<1><<<dim3(8, 64), 256, 0, stream>>>(
        attn_b, wproj_t, out, nullptr, bproj, 8192, 1024, 1024);
}

// Round 19
// 257.335 us; speedup vs baseline: 1.3168x; 1.0431x over previous
//
#include <hip/hip_runtime.h>
#include <hip/hip_bf16.h>
#include <stdint.h>

#define B_ 4
#define T_ 2048
#define C_ 1024
#define H_ 16
#define D_ 64

typedef __attribute__((ext_vector_type(8))) short bf16x8;
typedef __attribute__((ext_vector_type(4))) short short4v;
typedef __attribute__((ext_vector_type(4))) float f32x4;

static __device__ __forceinline__ short f2bf(float f) {
    union { float f; unsigned u; } v; v.f = f;
    unsigned r = v.u + 0x7fffu + ((v.u >> 16) & 1u);
    return (short)(r >> 16);
}

static __device__ __forceinline__ float fast_exp2(float x) {
    float r;
    asm("v_exp_f32 %0, %1" : "=v"(r) : "v"(x));
    return r;
}

#define GLD_LDS16(g, l) __builtin_amdgcn_global_load_lds( \
    (const __attribute__((address_space(1))) void*)(g),   \
    (__attribute__((address_space(3))) void*)(l), 16, 0, 0)

// Q pre-scale: (1/32) * log2(e) — folds softmax scale AND exp->exp2 conversion
#define QSCALE 0.04508422f

// ---------------------------------------------------------------------------
// pack_x (round-5 exact)
// ---------------------------------------------------------------------------
__global__ void pack_x(const float* __restrict__ x, short* __restrict__ xb) {
    int t = blockIdx.x * blockDim.x + threadIdx.x;
    const float* src = x + (size_t)t * 8;
    float4 v0 = *(const float4*)src;
    float4 v1 = *(const float4*)(src + 4);
    bf16x8 o;
    o[0] = f2bf(v0.x); o[1] = f2bf(v0.y); o[2] = f2bf(v0.z); o[3] = f2bf(v0.w);
    o[4] = f2bf(v1.x); o[5] = f2bf(v1.y); o[6] = f2bf(v1.z); o[7] = f2bf(v1.w);
    *(bf16x8*)(xb + (size_t)t * 8) = o;
}

// ---------------------------------------------------------------------------
// pack_wqkv2 / pack_wproj2 (round-12 exact, coalesced LDS-transpose)
// ---------------------------------------------------------------------------
__global__ void pack_wqkv2(const float* __restrict__ wq, const float* __restrict__ wk,
                           const float* __restrict__ wv, short* __restrict__ out) {
    __shared__ short tile[64][72];
    const int qh = blockIdx.y;
    const int qkv = qh >> 4, h = qh & 15;
    const int c0 = blockIdx.x * 64;
    const float* w = ((qkv == 0) ? wq : (qkv == 1) ? wk : wv) + (size_t)h * (C_ * D_);
    const int t = threadIdx.x;
    const int r = t >> 2;
    const int dc = (t & 3) * 16;

    const float* src = w + (size_t)(c0 + r) * D_ + dc;
#pragma unroll
    for (int j = 0; j < 4; ++j) {
        float4 v = *(const float4*)(src + j * 4);
        short4v s;
        s[0] = f2bf(v.x); s[1] = f2bf(v.y); s[2] = f2bf(v.z); s[3] = f2bf(v.w);
        *(short4v*)&tile[r][dc + j * 4] = s;
    }
    __syncthreads();

    const int d = t >> 2;
    const int cc = (t & 3) * 16;
    bf16x8 o0, o1;
#pragma unroll
    for (int j = 0; j < 8; ++j) {
        o0[j] = tile[cc + j][d];
        o1[j] = tile[cc + 8 + j][d];
    }
    short* dst = out + ((size_t)qkv * 1024 + h * 64 + d) * C_ + c0 + cc;
    *(bf16x8*)dst = o0;
    *(bf16x8*)(dst + 8) = o1;
}

__global__ void pack_wproj2(const float* __restrict__ wp, short* __restrict__ out) {
    __shared__ short tile[64][72];
    const int c0 = blockIdx.x * 64;
    const int n0 = blockIdx.y * 64;
    const int t = threadIdx.x;
    const int r = t >> 2;
    const int nc = (t & 3) * 16;

    const float* src = wp + (size_t)(c0 + r) * C_ + n0 + nc;
#pragma unroll
    for (int j = 0; j < 4; ++j) {
        float4 v = *(const float4*)(src + j * 4);
        short4v s;
        s[0] = f2bf(v.x); s[1] = f2bf(v.y); s[2] = f2bf(v.z); s[3] = f2bf(v.w);
        *(short4v*)&tile[r][nc + j * 4] = s;
    }
    __syncthreads();

    const int n = t >> 2;
    const int cc = (t & 3) * 16;
    bf16x8 o0, o1;
#pragma unroll
    for (int j = 0; j < 8; ++j) {
        o0[j] = tile[cc + j][n];
        o1[j] = tile[cc + 8 + j][n];
    }
    short* dst = out + (size_t)(n0 + n) * C_ + c0 + cc;
    *(bf16x8*)dst = o0;
    *(bf16x8*)(dst + 8) = o1;
}

// ---------------------------------------------------------------------------
// GEMM v15 (BK=64 + both-sides chunk-XOR) + T1 XCD-aware block swizzle
// (round-18 exact).
// ---------------------------------------------------------------------------
template<int MODE>
__global__ __launch_bounds__(256)
void gemm_lds(const short* __restrict__ A, const short* __restrict__ Bt,
              void* __restrict__ Cptr, short* __restrict__ vtptr,
              const float* __restrict__ bias, int M, int N, int K) {
    __shared__ short As[128 * 64];
    __shared__ short Bs[128 * 64];
    const int tid = threadIdx.x;
    const int lane = tid & 63, wid = tid >> 6;
    const int wr = wid >> 1, wc = wid & 1;
    const int l15 = lane & 15, l4 = lane >> 4;

    // T1: XCD-aware block remap (8 XCDs; nwg % 8 == 0 -> simple bijection)
    const int nwg = gridDim.x * gridDim.y;
    const int bid = blockIdx.y * gridDim.x + blockIdx.x;
    const int cpx = nwg >> 3;
    const int swz = (bid & 7) * cpx + (bid >> 3);
    const int m0 = (swz / gridDim.x) * 128;
    const int n0 = (swz % gridDim.x) * 128;

    f32x4 acc[4][4] = {};

    for (int k0 = 0; k0 < K; k0 += 64) {
#pragma unroll
        for (int p = 0; p < 4; ++p) {
            int e = p * 256 + tid;
            int r = e >> 3, pc = e & 7;
            int lc = pc ^ (r & 7);   // logical 16B k-chunk this slot holds
            GLD_LDS16(A  + (size_t)(m0 + r) * K + k0 + lc * 8, As + e * 8);
            GLD_LDS16(Bt + (size_t)(n0 + r) * K + k0 + lc * 8, Bs + e * 8);
        }
        __syncthreads();

#pragma unroll
        for (int kk = 0; kk < 2; ++kk) {
            bf16x8 af[4], bfr[4];
#pragma unroll
            for (int m = 0; m < 4; ++m) {
                int row = wr * 64 + m * 16 + l15;
                int pc = (kk * 4 + l4) ^ (row & 7);
                af[m] = *(const bf16x8*)(As + row * 64 + pc * 8);
            }
#pragma unroll
            for (int n = 0; n < 4; ++n) {
                int row = wc * 64 + n * 16 + l15;
                int pc = (kk * 4 + l4) ^ (row & 7);
                bfr[n] = *(const bf16x8*)(Bs + row * 64 + pc * 8);
            }
#pragma unroll
            for (int m = 0; m < 4; ++m)
#pragma unroll
                for (int n = 0; n < 4; ++n)
                    acc[m][n] = __builtin_amdgcn_mfma_f32_16x16x32_bf16(af[m], bfr[n], acc[m][n], 0, 0, 0);
        }
        __syncthreads();
    }

#pragma unroll
    for (int m = 0; m < 4; ++m) {
        int row_base = m0 + wr * 64 + m * 16 + l4 * 4;
#pragma unroll
        for (int n = 0; n < 4; ++n) {
            int col = n0 + wc * 64 + n * 16 + l15;
            if (MODE == 1) {
#pragma unroll
                for (int r = 0; r < 4; ++r)
                    ((float*)Cptr)[(size_t)(row_base + r) * N + col] =
                        acc[m][n][r] + bias[col];
            } else {  // MODE 2
                if (col < 2048) {  // Q (scaled) | K
                    float q = (col < 1024) ? QSCALE : 1.0f;
#pragma unroll
                    for (int r = 0; r < 4; ++r)
                        ((short*)Cptr)[(size_t)(row_base + r) * 2048 + col] =
                            f2bf(acc[m][n][r] * q);
                } else {           // V: transposed scatter
                    int cm = col - 2048;
                    int bq = row_base >> 11, t = row_base & 2047;
                    short4v s;
                    s[0] = f2bf(acc[m][n][0]); s[1] = f2bf(acc[m][n][1]);
                    s[2] = f2bf(acc[m][n][2]); s[3] = f2bf(acc[m][n][3]);
                    *(short4v*)(vtptr + ((size_t)bq * 1024 + cm) * 2048 + t) = s;
                }
            }
        }
    }
}

// ---------------------------------------------------------------------------
// Flash attention v19 = v16 + MFMA-based softmax row-sum:
//   psum VALU reduction (16 adds + 16 shfl_xor per strip-tile) replaced by
//   2 MFMAs against an all-ones B-fragment in pv(): D1 = P x 1 -> row sums
//   land at the same (l4*4+r) rows as O; srow[r] += D1[r].
//   Denominator now sums bf16-rounded P — consistent with the numerator.
// ---------------------------------------------------------------------------
__device__ __forceinline__ void softmax_phase(
    f32x4 S[4], f32x4 O[4], float* mrow, float* srow,
    int qrow0, int s0, bool diag, int l15, int l4, short* ps) {
    float pmax[4];
#pragma unroll
    for (int r = 0; r < 4; ++r) pmax[r] = -1e30f;
#pragma unroll
    for (int n = 0; n < 4; ++n) {
#pragma unroll
        for (int r = 0; r < 4; ++r) {
            float v = S[n][r];   // already scaled + in log2 domain
            if (diag) {
                int scol = s0 + n * 16 + l15;
                if (scol > qrow0 + r) v = -1e30f;
            }
            S[n][r] = v;
            pmax[r] = fmaxf(pmax[r], v);
        }
    }
#pragma unroll
    for (int r = 0; r < 4; ++r) {
        float v = pmax[r];
        v = fmaxf(v, __shfl_xor(v, 1));
        v = fmaxf(v, __shfl_xor(v, 2));
        v = fmaxf(v, __shfl_xor(v, 4));
        v = fmaxf(v, __shfl_xor(v, 8));
        pmax[r] = v;
    }
    // defer-max: skip O/s rescale while max growth <= 8 (P bounded by 2^8)
    int ok = (pmax[0] <= mrow[0] + 8.0f) & (pmax[1] <= mrow[1] + 8.0f) &
             (pmax[2] <= mrow[2] + 8.0f) & (pmax[3] <= mrow[3] + 8.0f);
    if (!__all(ok)) {
#pragma unroll
        for (int r = 0; r < 4; ++r) {
            float mnew = fmaxf(mrow[r], pmax[r]);
            float fr = fast_exp2(mrow[r] - mnew);
            mrow[r] = mnew;
            srow[r] *= fr;
#pragma unroll
            for (int n = 0; n < 4; ++n) O[n][r] *= fr;
        }
    }
    // exp + P->LDS only; row-sum now done via MFMA in pv()
#pragma unroll
    for (int n = 0; n < 4; ++n) {
#pragma unroll
        for (int r = 0; r < 4; ++r) {
            float p = fast_exp2(S[n][r] - mrow[r]);
            ps[(l4 * 4 + r) * 72 + n * 16 + l15] = f2bf(p);
        }
    }
}

__global__ __launch_bounds__(256)
void attn_v19(const short* __restrict__ qk, const short* __restrict__ vt,
              short* __restrict__ out) {
    const int pi = blockIdx.x;        // 0..15  (strip pair)
    const int bh = blockIdx.y;        // 0..63
    const int b = bh >> 4;
    const int h = bh & 15;
    const int qA0 = pi * 64;
    const int qB0 = (31 - pi) * 64;
    const int ntA = pi + 1;
    const int ntB = 32 - pi;
    const int tid = threadIdx.x;
    const int wave = tid >> 6;
    const int lane = tid & 63;
    const int l15 = lane & 15, l4 = lane >> 4;

    __shared__ short Vt[2][64][64];     // linear (GLD dest); source-swizzled
    __shared__ short Ps[4][2][16][72];  // per-wave, per-strip P buffer

    const size_t rs = 2 * C_;  // 2048
    const short* qbA = qk + ((size_t)b * T_ + qA0) * rs + h * 64;
    const short* qbB = qk + ((size_t)b * T_ + qB0) * rs + h * 64;
    const short* kb  = qk + (size_t)b * T_ * rs + 1024 + h * 64;
    const short* vtb = vt + (size_t)bh * 64 * T_;   // V^T rows [d][t]

    bf16x8 aqA0 = *(const bf16x8*)(qbA + (size_t)(wave * 16 + l15) * rs + l4 * 8);
    bf16x8 aqA1 = *(const bf16x8*)(qbA + (size_t)(wave * 16 + l15) * rs + 32 + l4 * 8);
    bf16x8 aqB0 = *(const bf16x8*)(qbB + (size_t)(wave * 16 + l15) * rs + l4 * 8);
    bf16x8 aqB1 = *(const bf16x8*)(qbB + (size_t)(wave * 16 + l15) * rs + 32 + l4 * 8);

    // all-ones bf16 B-fragment for the MFMA row-sum (bf16 1.0 = 0x3F80)
    bf16x8 vone;
#pragma unroll
    for (int j = 0; j < 8; ++j) vone[j] = (short)0x3F80;

    f32x4 OA[4] = {}, OB[4] = {};
    float mA[4], sA[4], mB[4], sB[4];
#pragma unroll
    for (int r = 0; r < 4; ++r) { mA[r] = mB[r] = -1e30f; sA[r] = sB[r] = 0.0f; }

    short* psB = &Ps[wave][0][0][0];
    short* psA = &Ps[wave][1][0][0];
    const int qrB = qB0 + wave * 16 + l4 * 4;
    const int qrA = qA0 + wave * 16 + l4 * 4;

    // staging geometry: slot e covers row r=e>>3, physical chunk pc=e&7;
    // source column chunk lc = pc ^ (r&7)  (both-sides XOR swizzle)
    const int sr = tid >> 3;                 // row this thread covers (p=0)
    const int spc = tid & 7;

    auto stage = [&](int slot, int s0) {
#pragma unroll
        for (int p = 0; p < 2; ++p) {
            int e = p * 256 + tid;
            int r = (p == 0) ? sr : (sr + 32);
            int lc = spc ^ (r & 7);
            GLD_LDS16(vtb + (size_t)r * T_ + s0 + lc * 8,
                      &Vt[slot][0][0] + e * 8);
        }
    };

    auto qk_sm = [&](int s0, bool actA) {
        bf16x8 bk0[4], bk1[4];
#pragma unroll
        for (int n = 0; n < 4; ++n) {
            const short* kr = kb + (size_t)(s0 + n * 16 + l15) * rs;
            bk0[n] = *(const bf16x8*)(kr + l4 * 8);
            bk1[n] = *(const bf16x8*)(kr + 32 + l4 * 8);
        }
        f32x4 S[4];
#pragma unroll
        for (int n = 0; n < 4; ++n) {
            f32x4 z = {};
            z = __builtin_amdgcn_mfma_f32_16x16x32_bf16(aqB0, bk0[n], z, 0, 0, 0);
            S[n] = __builtin_amdgcn_mfma_f32_16x16x32_bf16(aqB1, bk1[n], z, 0, 0, 0);
        }
        softmax_phase(S, OB, mB, sB, qrB, s0, s0 == qB0, l15, l4, psB);
        if (actA) {
            f32x4 SA[4];
#pragma unroll
            for (int n = 0; n < 4; ++n) {
                f32x4 z = {};
                z = __builtin_amdgcn_mfma_f32_16x16x32_bf16(aqA0, bk0[n], z, 0, 0, 0);
                SA[n] = __builtin_amdgcn_mfma_f32_16x16x32_bf16(aqA1, bk1[n], z, 0, 0, 0);
            }
            softmax_phase(SA, OA, mA, sA, qrA, s0, s0 == qA0, l15, l4, psA);
        }
    };

    auto pv = [&](int slot, bool actA) {
        bf16x8 apB0 = *(const bf16x8*)(psB + l15 * 72 + l4 * 8);
        bf16x8 apB1 = *(const bf16x8*)(psB + l15 * 72 + 32 + l4 * 8);
        const int x7 = l15 & 7;
        // MFMA row-sum: D1 = P x ones -> psum at rows l4*4+r (all cols equal)
        f32x4 d1 = {};
        d1 = __builtin_amdgcn_mfma_f32_16x16x32_bf16(apB0, vone, d1, 0, 0, 0);
        d1 = __builtin_amdgcn_mfma_f32_16x16x32_bf16(apB1, vone, d1, 0, 0, 0);
#pragma unroll
        for (int r = 0; r < 4; ++r) sB[r] += d1[r];
#pragma unroll
        for (int n = 0; n < 4; ++n) {
            const short* vrow = &Vt[slot][n * 16 + l15][0];
            bf16x8 bv0 = *(const bf16x8*)(vrow + ((l4 ^ x7) * 8));
            bf16x8 bv1 = *(const bf16x8*)(vrow + (((l4 + 4) ^ x7) * 8));
            OB[n] = __builtin_amdgcn_mfma_f32_16x16x32_bf16(apB0, bv0, OB[n], 0, 0, 0);
            OB[n] = __builtin_amdgcn_mfma_f32_16x16x32_bf16(apB1, bv1, OB[n], 0, 0, 0);
        }
        if (actA) {
            bf16x8 apA0 = *(const bf16x8*)(psA + l15 * 72 + l4 * 8);
            bf16x8 apA1 = *(const bf16x8*)(psA + l15 * 72 + 32 + l4 * 8);
            f32x4 dA = {};
            dA = __builtin_amdgcn_mfma_f32_16x16x32_bf16(apA0, vone, dA, 0, 0, 0);
            dA = __builtin_amdgcn_mfma_f32_16x16x32_bf16(apA1, vone, dA, 0, 0, 0);
#pragma unroll
            for (int r = 0; r < 4; ++r) sA[r] += dA[r];
#pragma unroll
            for (int n = 0; n < 4; ++n) {
                const short* vrow = &Vt[slot][n * 16 + l15][0];
                bf16x8 bv0 = *(const bf16x8*)(vrow + ((l4 ^ x7) * 8));
                bf16x8 bv1 = *(const bf16x8*)(vrow + (((l4 + 4) ^ x7) * 8));
                OA[n] = __builtin_amdgcn_mfma_f32_16x16x32_bf16(apA0, bv0, OA[n], 0, 0, 0);
                OA[n] = __builtin_amdgcn_mfma_f32_16x16x32_bf16(apA1, bv1, OA[n], 0, 0, 0);
            }
        }
    };

    const int npair = ntB & ~1;
    for (int t = 0; t < npair; t += 2) {
        const int s0 = t * 64;
        __syncthreads();  // both Vt slots free (all PV reads of prev pair done)

        // ---- issue V(t), V(t+1) via global_load_lds (fire-and-forget) ----
        stage(0, s0);
        stage(1, s0 + 64);

        qk_sm(s0, t < ntA);   // GLD latency hides under QK^T + softmax

        __syncthreads();      // vmcnt(0): V staged; Ps(t) drained

        pv(0, t < ntA);
        qk_sm(s0 + 64, t + 1 < ntA);

        asm volatile("s_waitcnt lgkmcnt(0)" ::: "memory");
        __builtin_amdgcn_sched_barrier(0);

        pv(1, t + 1 < ntA);
    }

    if (ntB & 1) {  // odd tail: single tile
        const int s0 = npair * 64;
        __syncthreads();
        stage(0, s0);
        qk_sm(s0, npair < ntA);
        __syncthreads();
        pv(0, npair < ntA);
    }

    // ---- normalize + store both strips ----
#pragma unroll
    for (int r = 0; r < 4; ++r) {
        int rowB = qB0 + wave * 16 + l4 * 4 + r;
        int rowA = qA0 + wave * 16 + l4 * 4 + r;
        float invB = 1.0f / sB[r];
        float invA = 1.0f / sA[r];
        size_t obB = ((size_t)b * T_ + rowB) * C_ + h * 64;
        size_t obA = ((size_t)b * T_ + rowA) * C_ + h * 64;
#pragma unroll
        for (int n = 0; n < 4; ++n) {
            out[obB + n * 16 + l15] = f2bf(OB[n][r] * invB);
            out[obA + n * 16 + l15] = f2bf(OA[n][r] * invA);
        }
    }
}

// ---------------------------------------------------------------------------
extern "C" void kernel_launch(void* const* d_in, const int* in_sizes, int n_in,
                              void* d_out, int out_size, void* d_ws, size_t ws_size,
                              hipStream_t stream) {
    const float* x     = (const float*)d_in[0];
    const float* wq    = (const float*)d_in[1];
    const float* wk    = (const float*)d_in[2];
    const float* wv    = (const float*)d_in[3];
    const float* wproj = (const float*)d_in[4];
    const float* bproj = (const float*)d_in[5];
    float* out = (float*)d_out;

    // workspace (shorts): wqkv_t | wproj_t | qk_b | vt_b | attn_b (xb alias)
    short* wqkv_t  = (short*)d_ws;                   // 3072*1024
    short* wproj_t = wqkv_t + 3072 * 1024;           // 1024*1024
    short* qk_b    = wproj_t + 1024 * 1024;          // 8192*2048  (Q|K)
    short* vt_b    = qk_b + (size_t)8192 * 2048;     // 64*64*2048 (V^T)
    short* attn_b  = vt_b + (size_t)64 * 64 * 2048;  // 8192*1024 (xb alias)
    short* xb      = attn_b;
    // total = 75,497,472 bytes (identical to all prior rounds)

    pack_x<<<4096, 256, 0, stream>>>(x, xb);
    pack_wqkv2<<<dim3(16, 48), 256, 0, stream>>>(wq, wk, wv, wqkv_t);
    pack_wproj2<<<dim3(16, 16), 256, 0, stream>>>(wproj, wproj_t);

    // QKV projection: Q(scaled)|K -> qk_b, V^T -> vt_b
    gemm_lds<2><<<dim3(24, 64), 256, 0, stream>>>(
        xb, wqkv_t, qk_b, vt_b, nullptr, 8192, 3072, 1024);

    // flash attention, pair-tile phases, GLD V-staging, MFMA row-sum
    attn_v19<<<dim3(16, 64), 256, 0, stream>>>(qk_b, vt_b, attn_b);

    // output projection: [8192,1024] x [1024,1024] + bias -> fp32
    gemm_lds<1><<<dim3(8, 64), 256, 0, stream>>>(
        attn_b, wproj_t, out, nullptr, bproj, 8192, 1024, 1024);
}